// Round 4
// baseline (2703.117 us; speedup 1.0000x reference)
//
#include <hip/hip_runtime.h>
#include <cstdint>
#include <cstddef>

// Problem constants (from reference setup_inputs)
#define NN 100000
#define EE 1600000
#define NMG 4000
// leaky_relu negative_slope = 0.01 (jax.nn.leaky_relu default)

// ---------------------------------------------------------------------------
// CSR build: histogram -> exclusive scan -> scatter (edge_index is reused by
// all 4 conv layers, so build once per call)
// ---------------------------------------------------------------------------
__global__ __launch_bounds__(256) void tf_hist(const int* __restrict__ dst, int* __restrict__ deg) {
    int j = blockIdx.x * 256 + threadIdx.x;
    if (j < EE) atomicAdd(&deg[dst[j]], 1);
}

__global__ __launch_bounds__(256) void tf_scan1(const int* __restrict__ deg, int* __restrict__ rp,
                                                int* __restrict__ part) {
    __shared__ int sm[256];
    int tid = threadIdx.x;
    int i = blockIdx.x * 256 + tid;
    int v = (i < NN) ? deg[i] : 0;
    sm[tid] = v;
    __syncthreads();
    for (int off = 1; off < 256; off <<= 1) {
        int t = (tid >= off) ? sm[tid - off] : 0;
        __syncthreads();
        sm[tid] += t;
        __syncthreads();
    }
    if (i < NN) rp[i] = sm[tid] - v;           // block-local exclusive
    if (tid == 255) part[blockIdx.x] = sm[255]; // block total
}

__global__ __launch_bounds__(512) void tf_scan2(const int* __restrict__ part, int* __restrict__ offs, int nb) {
    __shared__ int sm[512];
    int tid = threadIdx.x;
    int v = (tid < nb) ? part[tid] : 0;
    sm[tid] = v;
    __syncthreads();
    for (int off = 1; off < 512; off <<= 1) {
        int t = (tid >= off) ? sm[tid - off] : 0;
        __syncthreads();
        sm[tid] += t;
        __syncthreads();
    }
    if (tid < nb) offs[tid] = sm[tid] - v;      // exclusive
}

__global__ __launch_bounds__(256) void tf_scan3(int* __restrict__ rp, const int* __restrict__ offs) {
    int i = blockIdx.x * 256 + threadIdx.x;
    if (i < NN) rp[i] += offs[i >> 8];
    else if (i == NN) rp[NN] = EE;
}

__global__ __launch_bounds__(256) void tf_scatter(const int* __restrict__ src, const int* __restrict__ dst,
                                                  const int* __restrict__ rp, int* __restrict__ cur,
                                                  int* __restrict__ ssrc, int* __restrict__ seid) {
    int j = blockIdx.x * 256 + threadIdx.x;
    if (j >= EE) return;
    int d = dst[j];
    int pos = atomicAdd(&cur[d], 1);
    int slot = rp[d] + pos;
    ssrc[slot] = src[j];
    seid[slot] = j;
}

// ---------------------------------------------------------------------------
// f32 GEMM, tile: 64 rows x 256 cols, BK=16; 256 threads, 4x16 micro-tile.
// MODE 0: conv projections -> 4 weight mats [K,64], 4 outputs [N,64] (Q,K,V,BASE)
// MODE 1: classifier-1, A gathered as concat(hs0|hs1|hs2|pool[batch]) (K=256)
// MODE 2: plain [N,256] @ [256,256] with optional leaky epilogue
// ---------------------------------------------------------------------------
template <int MODE>
__global__ __launch_bounds__(256) void tf_gemm(
    const float* __restrict__ A,
    const float* __restrict__ hs0, const float* __restrict__ hs1,
    const float* __restrict__ hs2, const float* __restrict__ pl,
    const int* __restrict__ batch,
    const float* __restrict__ W0, const float* __restrict__ W1p,
    const float* __restrict__ W2, const float* __restrict__ W3,
    const float* __restrict__ b0, const float* __restrict__ b1p,
    const float* __restrict__ b2, const float* __restrict__ b3,
    float* __restrict__ O0, float* __restrict__ O1,
    float* __restrict__ O2, float* __restrict__ O3,
    int Kdim, int act) {
    __shared__ float As[64][17];   // +1 pad breaks bank aliasing on column reads
    __shared__ float Bs[16][256];
    int tid = threadIdx.x;
    int tx = tid & 15, ty = tid >> 4;
    int bm = blockIdx.x * 64;
    int txc = tx * 16;
    float acc[4][16];
#pragma unroll
    for (int j = 0; j < 4; ++j)
#pragma unroll
        for (int i = 0; i < 16; ++i) acc[j][i] = 0.f;

    int arow = tid >> 2;        // 0..63
    int aq = (tid & 3) * 4;     // 0,4,8,12
    int grow = bm + arow;

    for (int k0 = 0; k0 < Kdim; k0 += 16) {
        // ---- A tile (64x16), one float4 per thread
        float4 av = make_float4(0.f, 0.f, 0.f, 0.f);
        if (grow < NN) {
            if (MODE == 1) {
                int k = k0 + aq, g = k >> 6, c = k & 63;
                if (g == 3) av = *(const float4*)(pl + (size_t)batch[grow] * 64 + c);
                else {
                    const float* s = (g == 0) ? hs0 : (g == 1) ? hs1 : hs2;
                    av = *(const float4*)(s + (size_t)grow * 64 + c);
                }
            } else {
                av = *(const float4*)(A + (size_t)grow * Kdim + k0 + aq);
            }
        }
        As[arow][aq + 0] = av.x; As[arow][aq + 1] = av.y;
        As[arow][aq + 2] = av.z; As[arow][aq + 3] = av.w;
        // ---- B tile (16x256), 4 float4 per thread
#pragma unroll
        for (int r = 0; r < 4; ++r) {
            int f4 = tid + r * 256;       // 0..1023
            int t = f4 >> 6;              // 0..15
            int col = (f4 & 63) * 4;      // 0..252
            float4 bv;
            if (MODE == 0) {
                int g = col >> 6, c = col & 63;
                const float* Wg = (g == 0) ? W0 : (g == 1) ? W1p : (g == 2) ? W2 : W3;
                bv = *(const float4*)(Wg + (size_t)(k0 + t) * 64 + c);
            } else {
                bv = *(const float4*)(W0 + (size_t)(k0 + t) * 256 + col);
            }
            *(float4*)&Bs[t][col] = bv;
        }
        __syncthreads();
#pragma unroll
        for (int t = 0; t < 16; ++t) {
            float a0 = As[ty * 4 + 0][t], a1 = As[ty * 4 + 1][t];
            float a2 = As[ty * 4 + 2][t], a3 = As[ty * 4 + 3][t];
            float4 v0 = *(const float4*)&Bs[t][txc + 0];
            float4 v1 = *(const float4*)&Bs[t][txc + 4];
            float4 v2 = *(const float4*)&Bs[t][txc + 8];
            float4 v3 = *(const float4*)&Bs[t][txc + 12];
            float bb[16] = {v0.x, v0.y, v0.z, v0.w, v1.x, v1.y, v1.z, v1.w,
                            v2.x, v2.y, v2.z, v2.w, v3.x, v3.y, v3.z, v3.w};
#pragma unroll
            for (int i = 0; i < 16; ++i) {
                acc[0][i] = fmaf(a0, bb[i], acc[0][i]);
                acc[1][i] = fmaf(a1, bb[i], acc[1][i]);
                acc[2][i] = fmaf(a2, bb[i], acc[2][i]);
                acc[3][i] = fmaf(a3, bb[i], acc[3][i]);
            }
        }
        __syncthreads();
    }
    // ---- epilogue
    if (MODE == 0) {
        int g = tx >> 2;
        const float* bias = (g == 0) ? b0 : (g == 1) ? b1p : (g == 2) ? b2 : b3;
        float* Out = (g == 0) ? O0 : (g == 1) ? O1 : (g == 2) ? O2 : O3;
        int cb = (tx & 3) * 16;
#pragma unroll
        for (int j = 0; j < 4; ++j) {
            int r = bm + ty * 4 + j;
            if (r < NN) {
#pragma unroll
                for (int i = 0; i < 16; i += 4) {
                    float4 v;
                    v.x = acc[j][i + 0] + bias[cb + i + 0];
                    v.y = acc[j][i + 1] + bias[cb + i + 1];
                    v.z = acc[j][i + 2] + bias[cb + i + 2];
                    v.w = acc[j][i + 3] + bias[cb + i + 3];
                    *(float4*)(Out + (size_t)r * 64 + cb + i) = v;
                }
            }
        }
    } else {
#pragma unroll
        for (int j = 0; j < 4; ++j) {
            int r = bm + ty * 4 + j;
            if (r < NN) {
#pragma unroll
                for (int i = 0; i < 16; i += 4) {
                    int col = txc + i;
                    float4 v;
                    v.x = acc[j][i + 0] + b0[col + 0];
                    v.y = acc[j][i + 1] + b0[col + 1];
                    v.z = acc[j][i + 2] + b0[col + 2];
                    v.w = acc[j][i + 3] + b0[col + 3];
                    if (act) {
                        v.x = v.x > 0.f ? v.x : 0.01f * v.x;
                        v.y = v.y > 0.f ? v.y : 0.01f * v.y;
                        v.z = v.z > 0.f ? v.z : 0.01f * v.z;
                        v.w = v.w > 0.f ? v.w : 0.01f * v.w;
                    }
                    *(float4*)(O0 + (size_t)r * 256 + col) = v;
                }
            }
        }
    }
}

// ---------------------------------------------------------------------------
// Edge attention aggregation: one wave per destination node, lane = channel.
// Online (flash-style) softmax over incident edges; e = edge_attr @ We
// recomputed in-register (We column held in 16 VGPRs per lane).
// Epilogue adds skip (BASE = h@Ws+bs) and applies leaky_relu.
// ---------------------------------------------------------------------------
__global__ __launch_bounds__(256) void tf_agg(
    const float* __restrict__ Q, const float* __restrict__ Km,
    const float* __restrict__ V, const float* __restrict__ BASE,
    const int* __restrict__ rp, const int* __restrict__ ssrc, const int* __restrict__ seid,
    const float* __restrict__ ea, const float* __restrict__ We,
    float* __restrict__ out) {
    int node = (blockIdx.x << 2) + (threadIdx.x >> 6);
    int lane = threadIdx.x & 63;
    if (node >= NN) return;
    float w[16];
#pragma unroll
    for (int t = 0; t < 16; ++t) w[t] = We[t * 64 + lane];
    float q = Q[(size_t)node * 64 + lane];
    int beg = rp[node], end = rp[node + 1];
    float m = -INFINITY, s = 0.f, acc = 0.f;
    for (int it = beg; it < end; ++it) {
        int sj = ssrc[it];
        int ej = seid[it];
        const float4* eap = (const float4*)(ea + (size_t)ej * 16);
        float4 c0 = eap[0], c1 = eap[1], c2 = eap[2], c3 = eap[3];
        float e0 = c0.x * w[0] + c0.y * w[1] + c0.z * w[2] + c0.w * w[3];
        float e1 = c1.x * w[4] + c1.y * w[5] + c1.z * w[6] + c1.w * w[7];
        float e2 = c2.x * w[8] + c2.y * w[9] + c2.z * w[10] + c2.w * w[11];
        float e3 = c3.x * w[12] + c3.y * w[13] + c3.z * w[14] + c3.w * w[15];
        float e = (e0 + e1) + (e2 + e3);
        float kv = Km[(size_t)sj * 64 + lane] + e;
        float vv = V[(size_t)sj * 64 + lane] + e;
        float prod = q * kv;
#pragma unroll
        for (int o = 32; o; o >>= 1) prod += __shfl_xor(prod, o);
        float alpha = prod * 0.125f;  // 1/sqrt(64)
        float nm = fmaxf(m, alpha);
        float sc = __expf(m - nm);    // first iter: exp(-inf)=0
        float p = __expf(alpha - nm);
        s = s * sc + p;
        acc = acc * sc + p * vv;
        m = nm;
    }
    float o = acc / (s + 1e-16f) + BASE[(size_t)node * 64 + lane];
    out[(size_t)node * 64 + lane] = (o > 0.f) ? o : 0.01f * o;
}

// global_add_pool via atomics (batch sorted; optimize later if hot)
__global__ __launch_bounds__(256) void tf_pool(const float* __restrict__ h, const int* __restrict__ bat,
                                               float* __restrict__ pl) {
    int idx = blockIdx.x * 256 + threadIdx.x;   // exactly N*64
    if (idx >= NN * 64) return;
    int node = idx >> 6, l = idx & 63;
    atomicAdd(&pl[(size_t)bat[node] * 64 + l], h[idx]);
}

// final row-dot (256) + sigmoid; one wave per node
__global__ __launch_bounds__(256) void tf_final(const float* __restrict__ g, const float* __restrict__ Wf,
                                                const float* __restrict__ bf, float* __restrict__ out) {
    int wid = (blockIdx.x * 256 + threadIdx.x) >> 6;
    int lane = threadIdx.x & 63;
    if (wid >= NN) return;
    const float* row = g + (size_t)wid * 256;
    float s = row[lane] * Wf[lane] + row[lane + 64] * Wf[lane + 64] +
              row[lane + 128] * Wf[lane + 128] + row[lane + 192] * Wf[lane + 192];
#pragma unroll
    for (int off = 32; off; off >>= 1) s += __shfl_xor(s, off);
    if (lane == 0) out[wid] = 1.f / (1.f + __expf(-(s + bf[0])));
}

// ---------------------------------------------------------------------------
extern "C" void kernel_launch(void* const* d_in, const int* in_sizes, int n_in,
                              void* d_out, int out_size, void* d_ws, size_t ws_size,
                              hipStream_t stream) {
    (void)in_sizes; (void)n_in; (void)out_size; (void)ws_size;
    const float* x   = (const float*)d_in[0];
    const int*   ei  = (const int*)d_in[1];
    const float* ea  = (const float*)d_in[2];
    const int*   bat = (const int*)d_in[3];
    const float* Wq1 = (const float*)d_in[4];  const float* bq1 = (const float*)d_in[5];
    const float* Wk1 = (const float*)d_in[6];  const float* bk1 = (const float*)d_in[7];
    const float* Wv1 = (const float*)d_in[8];  const float* bv1 = (const float*)d_in[9];
    const float* We1 = (const float*)d_in[10];
    const float* Ws1 = (const float*)d_in[11]; const float* bs1 = (const float*)d_in[12];
    const float* WqL = (const float*)d_in[13]; const float* bqL = (const float*)d_in[14];
    const float* WkL = (const float*)d_in[15]; const float* bkL = (const float*)d_in[16];
    const float* WvL = (const float*)d_in[17]; const float* bvL = (const float*)d_in[18];
    const float* WeL = (const float*)d_in[19];
    const float* WsL = (const float*)d_in[20]; const float* bsL = (const float*)d_in[21];
    const float* W1  = (const float*)d_in[22]; const float* b1  = (const float*)d_in[23];
    const float* Wc  = (const float*)d_in[24]; const float* bc  = (const float*)d_in[25];
    const float* Wf  = (const float*)d_in[26]; const float* bf  = (const float*)d_in[27];
    float* outp = (float*)d_out;

    // workspace carve (~220 MB total)
    char* ws = (char*)d_ws;
    size_t off = 0;
    auto carve = [&](size_t bytes) {
        char* p = ws + off;
        off = (off + bytes + 255) & ~(size_t)255;
        return p;
    };
    int* rp    = (int*)carve((NN + 1) * sizeof(int));
    int* cur   = (int*)carve((size_t)NN * sizeof(int));   // doubles as degree histogram
    int* part  = (int*)carve(512 * sizeof(int));
    int* offs  = (int*)carve(512 * sizeof(int));
    int* ssrc  = (int*)carve((size_t)EE * sizeof(int));
    int* seid  = (int*)carve((size_t)EE * sizeof(int));
    float* bigA = (float*)carve((size_t)NN * 256 * sizeof(float)); // Q|K|V|BASE -> g1 -> g3
    float* bigB = (float*)carve((size_t)NN * 256 * sizeof(float)); // h0|hs0|hs1|hs2 -> g2
    float* pl   = (float*)carve((size_t)NMG * 64 * sizeof(float));

    float* Q    = bigA;
    float* Km   = bigA + (size_t)NN * 64;
    float* V    = bigA + (size_t)NN * 128;
    float* BASE = bigA + (size_t)NN * 192;
    float* h0   = bigB;
    float* hA   = bigB + (size_t)NN * 64;
    float* hB   = bigB + (size_t)NN * 128;
    float* hC   = bigB + (size_t)NN * 192;
    float* g1 = bigA;
    float* g2 = bigB;
    float* g3 = bigA;

    const int* esrc = ei;
    const int* edst = ei + EE;

    // ---- CSR build (once; reused by all 4 layers)
    hipMemsetAsync(cur, 0, (size_t)NN * sizeof(int), stream);
    tf_hist<<<EE / 256, 256, 0, stream>>>(edst, cur);
    tf_scan1<<<391, 256, 0, stream>>>(cur, rp, part);
    tf_scan2<<<1, 512, 0, stream>>>(part, offs, 391);
    tf_scan3<<<392, 256, 0, stream>>>(rp, offs);
    hipMemsetAsync(cur, 0, (size_t)NN * sizeof(int), stream);
    tf_scatter<<<EE / 256, 256, 0, stream>>>(esrc, edst, rp, cur, ssrc, seid);

    const int GB = (NN + 63) / 64;   // 1563 GEMM blocks
    const int AB = NN / 4;           // 25000 agg blocks

    // ---- conv1 (IN=128 -> 64)
    tf_gemm<0><<<GB, 256, 0, stream>>>(x, nullptr, nullptr, nullptr, nullptr, nullptr,
                                       Wq1, Wk1, Wv1, Ws1, bq1, bk1, bv1, bs1,
                                       Q, Km, V, BASE, 128, 0);
    tf_agg<<<AB, 256, 0, stream>>>(Q, Km, V, BASE, rp, ssrc, seid, ea, We1, h0);

    // ---- stacked convs (64 -> 64), outputs kept for classifier concat
    const float* hin = h0;
    float* houts[3] = {hA, hB, hC};
    for (int l = 0; l < 3; ++l) {
        tf_gemm<0><<<GB, 256, 0, stream>>>(hin, nullptr, nullptr, nullptr, nullptr, nullptr,
                                           WqL + l * 4096, WkL + l * 4096, WvL + l * 4096, WsL + l * 4096,
                                           bqL + l * 64, bkL + l * 64, bvL + l * 64, bsL + l * 64,
                                           Q, Km, V, BASE, 64, 0);
        tf_agg<<<AB, 256, 0, stream>>>(Q, Km, V, BASE, rp, ssrc, seid, ea, WeL + l * 1024, houts[l]);
        hin = houts[l];
    }

    // ---- global_add_pool on final h (hC)
    hipMemsetAsync(pl, 0, (size_t)NMG * 64 * sizeof(float), stream);
    tf_pool<<<AB, 256, 0, stream>>>(hC, bat, pl);

    // ---- classifier
    tf_gemm<1><<<GB, 256, 0, stream>>>(nullptr, hA, hB, hC, pl, bat,
                                       W1, nullptr, nullptr, nullptr,
                                       b1, nullptr, nullptr, nullptr,
                                       g1, nullptr, nullptr, nullptr, 256, 0);
    tf_gemm<2><<<GB, 256, 0, stream>>>(g1, nullptr, nullptr, nullptr, nullptr, nullptr,
                                       Wc, nullptr, nullptr, nullptr,
                                       bc, nullptr, nullptr, nullptr,
                                       g2, nullptr, nullptr, nullptr, 256, 1);
    tf_gemm<2><<<GB, 256, 0, stream>>>(g2, nullptr, nullptr, nullptr, nullptr, nullptr,
                                       Wc + 65536, nullptr, nullptr, nullptr,
                                       bc + 256, nullptr, nullptr, nullptr,
                                       g3, nullptr, nullptr, nullptr, 256, 1);
    tf_final<<<AB, 256, 0, stream>>>(g3, Wf, bf, outp);
}

// Round 5
// 2375.564 us; speedup vs baseline: 1.1379x; 1.1379x over previous
//
#include <hip/hip_runtime.h>
#include <cstdint>
#include <cstddef>

// Problem constants (from reference setup_inputs)
#define NN 100000
#define EE 1600000
#define NMG 4000
// leaky_relu negative_slope = 0.01 (jax.nn.leaky_relu default)

// ---------------------------------------------------------------------------
// CSR build: histogram -> exclusive scan -> scatter (edge_index reused by all
// 4 conv layers; built once per call)
// ---------------------------------------------------------------------------
__global__ __launch_bounds__(256) void tf_hist(const int* __restrict__ dst, int* __restrict__ deg) {
    int j = blockIdx.x * 256 + threadIdx.x;
    if (j < EE) atomicAdd(&deg[dst[j]], 1);
}

__global__ __launch_bounds__(256) void tf_scan1(const int* __restrict__ deg, int* __restrict__ rp,
                                                int* __restrict__ part) {
    __shared__ int sm[256];
    int tid = threadIdx.x;
    int i = blockIdx.x * 256 + tid;
    int v = (i < NN) ? deg[i] : 0;
    sm[tid] = v;
    __syncthreads();
    for (int off = 1; off < 256; off <<= 1) {
        int t = (tid >= off) ? sm[tid - off] : 0;
        __syncthreads();
        sm[tid] += t;
        __syncthreads();
    }
    if (i < NN) rp[i] = sm[tid] - v;           // block-local exclusive
    if (tid == 255) part[blockIdx.x] = sm[255]; // block total
}

__global__ __launch_bounds__(512) void tf_scan2(const int* __restrict__ part, int* __restrict__ offs, int nb) {
    __shared__ int sm[512];
    int tid = threadIdx.x;
    int v = (tid < nb) ? part[tid] : 0;
    sm[tid] = v;
    __syncthreads();
    for (int off = 1; off < 512; off <<= 1) {
        int t = (tid >= off) ? sm[tid - off] : 0;
        __syncthreads();
        sm[tid] += t;
        __syncthreads();
    }
    if (tid < nb) offs[tid] = sm[tid] - v;      // exclusive
}

__global__ __launch_bounds__(256) void tf_scan3(int* __restrict__ rp, const int* __restrict__ offs) {
    int i = blockIdx.x * 256 + threadIdx.x;
    if (i < NN) rp[i] += offs[i >> 8];
    else if (i == NN) rp[NN] = EE;
}

__global__ __launch_bounds__(256) void tf_scatter(const int* __restrict__ src, const int* __restrict__ dst,
                                                  const int* __restrict__ rp, int* __restrict__ cur,
                                                  int* __restrict__ ssrc, int* __restrict__ seid) {
    int j = blockIdx.x * 256 + threadIdx.x;
    if (j >= EE) return;
    int d = dst[j];
    int pos = atomicAdd(&cur[d], 1);
    int slot = rp[d] + pos;
    ssrc[slot] = src[j];
    seid[slot] = j;
}

// Reorder edge_attr into CSR slot order (sequential reads in tf_agg).
// One float4 per thread; 4 consecutive threads copy one 64B row.
__global__ __launch_bounds__(256) void tf_ecopy(const int* __restrict__ seid, const float* __restrict__ ea,
                                                float* __restrict__ eac) {
    size_t idx = (size_t)blockIdx.x * 256 + threadIdx.x;   // over EE*4 float4s
    if (idx >= (size_t)EE * 4) return;
    size_t slot = idx >> 2;
    int c4 = (int)(idx & 3);
    const float4* srcp = (const float4*)(ea + (size_t)seid[slot] * 16);
    ((float4*)(eac + slot * 16))[c4] = srcp[c4];
}

// ---------------------------------------------------------------------------
// f32 GEMM, tile: 64 rows x 256 cols, BK=16; 256 threads, 4x16 micro-tile.
// MODE 0: conv projections -> 4 weight mats [K,64], 4 outputs [N,64] (Q,K,V,BASE)
// MODE 1: classifier-1, A gathered as concat(hs0|hs1|hs2|pool[batch]) (K=256)
// MODE 2: plain [N,256] @ [256,256] with optional leaky epilogue
// ---------------------------------------------------------------------------
template <int MODE>
__global__ __launch_bounds__(256) void tf_gemm(
    const float* __restrict__ A,
    const float* __restrict__ hs0, const float* __restrict__ hs1,
    const float* __restrict__ hs2, const float* __restrict__ pl,
    const int* __restrict__ batch,
    const float* __restrict__ W0, const float* __restrict__ W1p,
    const float* __restrict__ W2, const float* __restrict__ W3,
    const float* __restrict__ b0, const float* __restrict__ b1p,
    const float* __restrict__ b2, const float* __restrict__ b3,
    float* __restrict__ O0, float* __restrict__ O1,
    float* __restrict__ O2, float* __restrict__ O3,
    int Kdim, int act) {
    __shared__ float As[64][17];   // +1 pad breaks bank aliasing on column reads
    __shared__ float Bs[16][256];
    int tid = threadIdx.x;
    int tx = tid & 15, ty = tid >> 4;
    int bm = blockIdx.x * 64;
    int txc = tx * 16;
    float acc[4][16];
#pragma unroll
    for (int j = 0; j < 4; ++j)
#pragma unroll
        for (int i = 0; i < 16; ++i) acc[j][i] = 0.f;

    int arow = tid >> 2;        // 0..63
    int aq = (tid & 3) * 4;     // 0,4,8,12
    int grow = bm + arow;

    for (int k0 = 0; k0 < Kdim; k0 += 16) {
        // ---- A tile (64x16), one float4 per thread
        float4 av = make_float4(0.f, 0.f, 0.f, 0.f);
        if (grow < NN) {
            if (MODE == 1) {
                int k = k0 + aq, g = k >> 6, c = k & 63;
                if (g == 3) av = *(const float4*)(pl + (size_t)batch[grow] * 64 + c);
                else {
                    const float* s = (g == 0) ? hs0 : (g == 1) ? hs1 : hs2;
                    av = *(const float4*)(s + (size_t)grow * 64 + c);
                }
            } else {
                av = *(const float4*)(A + (size_t)grow * Kdim + k0 + aq);
            }
        }
        As[arow][aq + 0] = av.x; As[arow][aq + 1] = av.y;
        As[arow][aq + 2] = av.z; As[arow][aq + 3] = av.w;
        // ---- B tile (16x256), 4 float4 per thread
#pragma unroll
        for (int r = 0; r < 4; ++r) {
            int f4 = tid + r * 256;       // 0..1023
            int t = f4 >> 6;              // 0..15
            int col = (f4 & 63) * 4;      // 0..252
            float4 bv;
            if (MODE == 0) {
                int g = col >> 6, c = col & 63;
                const float* Wg = (g == 0) ? W0 : (g == 1) ? W1p : (g == 2) ? W2 : W3;
                bv = *(const float4*)(Wg + (size_t)(k0 + t) * 64 + c);
            } else {
                bv = *(const float4*)(W0 + (size_t)(k0 + t) * 256 + col);
            }
            *(float4*)&Bs[t][col] = bv;
        }
        __syncthreads();
#pragma unroll
        for (int t = 0; t < 16; ++t) {
            float a0 = As[ty * 4 + 0][t], a1 = As[ty * 4 + 1][t];
            float a2 = As[ty * 4 + 2][t], a3 = As[ty * 4 + 3][t];
            float4 v0 = *(const float4*)&Bs[t][txc + 0];
            float4 v1 = *(const float4*)&Bs[t][txc + 4];
            float4 v2 = *(const float4*)&Bs[t][txc + 8];
            float4 v3 = *(const float4*)&Bs[t][txc + 12];
            float bb[16] = {v0.x, v0.y, v0.z, v0.w, v1.x, v1.y, v1.z, v1.w,
                            v2.x, v2.y, v2.z, v2.w, v3.x, v3.y, v3.z, v3.w};
#pragma unroll
            for (int i = 0; i < 16; ++i) {
                acc[0][i] = fmaf(a0, bb[i], acc[0][i]);
                acc[1][i] = fmaf(a1, bb[i], acc[1][i]);
                acc[2][i] = fmaf(a2, bb[i], acc[2][i]);
                acc[3][i] = fmaf(a3, bb[i], acc[3][i]);
            }
        }
        __syncthreads();
    }
    // ---- epilogue
    if (MODE == 0) {
        int g = tx >> 2;
        const float* bias = (g == 0) ? b0 : (g == 1) ? b1p : (g == 2) ? b2 : b3;
        float* Out = (g == 0) ? O0 : (g == 1) ? O1 : (g == 2) ? O2 : O3;
        int cb = (tx & 3) * 16;
#pragma unroll
        for (int j = 0; j < 4; ++j) {
            int r = bm + ty * 4 + j;
            if (r < NN) {
#pragma unroll
                for (int i = 0; i < 16; i += 4) {
                    float4 v;
                    v.x = acc[j][i + 0] + bias[cb + i + 0];
                    v.y = acc[j][i + 1] + bias[cb + i + 1];
                    v.z = acc[j][i + 2] + bias[cb + i + 2];
                    v.w = acc[j][i + 3] + bias[cb + i + 3];
                    *(float4*)(Out + (size_t)r * 64 + cb + i) = v;
                }
            }
        }
    } else {
#pragma unroll
        for (int j = 0; j < 4; ++j) {
            int r = bm + ty * 4 + j;
            if (r < NN) {
#pragma unroll
                for (int i = 0; i < 16; i += 4) {
                    int col = txc + i;
                    float4 v;
                    v.x = acc[j][i + 0] + b0[col + 0];
                    v.y = acc[j][i + 1] + b0[col + 1];
                    v.z = acc[j][i + 2] + b0[col + 2];
                    v.w = acc[j][i + 3] + b0[col + 3];
                    if (act) {
                        v.x = v.x > 0.f ? v.x : 0.01f * v.x;
                        v.y = v.y > 0.f ? v.y : 0.01f * v.y;
                        v.z = v.z > 0.f ? v.z : 0.01f * v.z;
                        v.w = v.w > 0.f ? v.w : 0.01f * v.w;
                    }
                    *(float4*)(O0 + (size_t)r * 256 + col) = v;
                }
            }
        }
    }
}

// ---------------------------------------------------------------------------
// Edge attention aggregation, one wave per dst node, lane = channel.
// Algebraic restructure:
//   alpha_j = (q.k[sj] + ea_j.qe)/8  where qe = We @ q (16-dim, computed once)
//   out_e   = (sum_j p_j ea_j) @ We  (16-wide pea accumulator, applied once)
// -> no per-edge 64-wide edge projection. Two independent online-softmax
// streams (even/odd edges) double the gather/shfl/exp ILP; merged at end.
// USE_EAC: read edge_attr in sequential CSR order (eac) vs random via seid.
// ---------------------------------------------------------------------------
template <bool USE_EAC>
__global__ __launch_bounds__(256) void tf_agg(
    const float* __restrict__ Q, const float* __restrict__ Km,
    const float* __restrict__ V, const float* __restrict__ BASE,
    const int* __restrict__ rp, const int* __restrict__ ssrc, const int* __restrict__ seid,
    const float* __restrict__ eaw,   // USE_EAC ? eac[EE,16] (slot order) : ea[EE,16] (orig order)
    const float* __restrict__ We,    // [16,64]
    float* __restrict__ out) {
    __shared__ float qsm[4][64];
    int wv = threadIdx.x >> 6;
    int node = (blockIdx.x << 2) + wv;
    int lane = threadIdx.x & 63;
    if (node >= NN) return;

    float w[16];
#pragma unroll
    for (int d = 0; d < 16; ++d) w[d] = We[d * 64 + lane];

    float q = Q[(size_t)node * 64 + lane];

    // ---- qe_d = sum_c We[d][c] * q[c], d = 0..15 (LDS transpose + 4-lane reduce)
    qsm[wv][lane] = q;
    int dgrp = lane >> 2;          // 16 d-groups x 4 lanes
    int cb = lane & 3;
    float pq = 0.f;
#pragma unroll
    for (int k2 = 0; k2 < 16; ++k2) {
        int c = cb + (k2 << 2);
        pq = fmaf(qsm[wv][c], We[dgrp * 64 + c], pq);
    }
    pq += __shfl_xor(pq, 1);
    pq += __shfl_xor(pq, 2);                      // all 4 lanes of group d hold qe_d
    float qel = __shfl(pq, (lane & 15) << 2);     // lane<16 -> qe[lane]

    int beg = rp[node], end = rp[node + 1];
    float mA = -INFINITY, sA = 0.f, accA = 0.f, peaA = 0.f;
    float mB = -INFINITY, sB = 0.f, accB = 0.f, peaB = 0.f;

    int it = beg;
    for (; it + 1 < end; it += 2) {
        int sa = ssrc[it], sb = ssrc[it + 1];
        float ea_a, ea_b;
        if (USE_EAC) {
            ea_a = (lane < 16) ? eaw[(size_t)it * 16 + lane] : 0.f;
            ea_b = (lane < 16) ? eaw[(size_t)(it + 1) * 16 + lane] : 0.f;
        } else {
            int ja = seid[it], jb = seid[it + 1];
            ea_a = (lane < 16) ? eaw[(size_t)ja * 16 + lane] : 0.f;
            ea_b = (lane < 16) ? eaw[(size_t)jb * 16 + lane] : 0.f;
        }
        float ka = Km[(size_t)sa * 64 + lane];
        float kb = Km[(size_t)sb * 64 + lane];
        float va = V[(size_t)sa * 64 + lane];
        float vb = V[(size_t)sb * 64 + lane];
        float pa = fmaf(q, ka, ea_a * qel);
        float pb = fmaf(q, kb, ea_b * qel);
#pragma unroll
        for (int o = 32; o; o >>= 1) {
            pa += __shfl_xor(pa, o);
            pb += __shfl_xor(pb, o);
        }
        float alA = pa * 0.125f, alB = pb * 0.125f;   // 1/sqrt(64)
        float nmA = fmaxf(mA, alA);
        float scA = __expf(mA - nmA);
        float ppA = __expf(alA - nmA);
        sA = sA * scA + ppA;
        accA = fmaf(ppA, va, accA * scA);
        peaA = fmaf(ppA, ea_a, peaA * scA);
        mA = nmA;
        float nmB = fmaxf(mB, alB);
        float scB = __expf(mB - nmB);
        float ppB = __expf(alB - nmB);
        sB = sB * scB + ppB;
        accB = fmaf(ppB, vb, accB * scB);
        peaB = fmaf(ppB, ea_b, peaB * scB);
        mB = nmB;
    }
    if (it < end) {   // odd tail -> stream A
        int sa = ssrc[it];
        float ea_a;
        if (USE_EAC) ea_a = (lane < 16) ? eaw[(size_t)it * 16 + lane] : 0.f;
        else {
            int ja = seid[it];
            ea_a = (lane < 16) ? eaw[(size_t)ja * 16 + lane] : 0.f;
        }
        float ka = Km[(size_t)sa * 64 + lane];
        float va = V[(size_t)sa * 64 + lane];
        float pa = fmaf(q, ka, ea_a * qel);
#pragma unroll
        for (int o = 32; o; o >>= 1) pa += __shfl_xor(pa, o);
        float alA = pa * 0.125f;
        float nmA = fmaxf(mA, alA);
        float scA = __expf(mA - nmA);
        float ppA = __expf(alA - nmA);
        sA = sA * scA + ppA;
        accA = fmaf(ppA, va, accA * scA);
        peaA = fmaf(ppA, ea_a, peaA * scA);
        mA = nmA;
    }

    float base = BASE[(size_t)node * 64 + lane];
    float o;
    if (end > beg) {
        float m = fmaxf(mA, mB);      // finite: stream A always has >=1 edge
        float cA = __expf(mA - m);
        float cB = __expf(mB - m);    // mB may be -inf -> 0
        float s = sA * cA + sB * cB;
        float acc = accA * cA + accB * cB;
        float pea = peaA * cA + peaB * cB;
        float eaout = 0.f;
#pragma unroll
        for (int d = 0; d < 16; ++d) eaout = fmaf(__shfl(pea, d), w[d], eaout);
        o = (acc + eaout) / (s + 1e-16f) + base;
    } else {
        o = base;                     // empty segment: softmax contributes 0
    }
    out[(size_t)node * 64 + lane] = (o > 0.f) ? o : 0.01f * o;
}

// global_add_pool via atomics (batch sorted)
__global__ __launch_bounds__(256) void tf_pool(const float* __restrict__ h, const int* __restrict__ bat,
                                               float* __restrict__ pl) {
    int idx = blockIdx.x * 256 + threadIdx.x;   // exactly N*64
    if (idx >= NN * 64) return;
    int node = idx >> 6, l = idx & 63;
    atomicAdd(&pl[(size_t)bat[node] * 64 + l], h[idx]);
}

// final row-dot (256) + sigmoid; one wave per node
__global__ __launch_bounds__(256) void tf_final(const float* __restrict__ g, const float* __restrict__ Wf,
                                                const float* __restrict__ bf, float* __restrict__ out) {
    int wid = (blockIdx.x * 256 + threadIdx.x) >> 6;
    int lane = threadIdx.x & 63;
    if (wid >= NN) return;
    const float* row = g + (size_t)wid * 256;
    float s = row[lane] * Wf[lane] + row[lane + 64] * Wf[lane + 64] +
              row[lane + 128] * Wf[lane + 128] + row[lane + 192] * Wf[lane + 192];
#pragma unroll
    for (int off = 32; off; off >>= 1) s += __shfl_xor(s, off);
    if (lane == 0) out[wid] = 1.f / (1.f + __expf(-(s + bf[0])));
}

// ---------------------------------------------------------------------------
extern "C" void kernel_launch(void* const* d_in, const int* in_sizes, int n_in,
                              void* d_out, int out_size, void* d_ws, size_t ws_size,
                              hipStream_t stream) {
    (void)in_sizes; (void)n_in; (void)out_size;
    const float* x   = (const float*)d_in[0];
    const int*   ei  = (const int*)d_in[1];
    const float* ea  = (const float*)d_in[2];
    const int*   bat = (const int*)d_in[3];
    const float* Wq1 = (const float*)d_in[4];  const float* bq1 = (const float*)d_in[5];
    const float* Wk1 = (const float*)d_in[6];  const float* bk1 = (const float*)d_in[7];
    const float* Wv1 = (const float*)d_in[8];  const float* bv1 = (const float*)d_in[9];
    const float* We1 = (const float*)d_in[10];
    const float* Ws1 = (const float*)d_in[11]; const float* bs1 = (const float*)d_in[12];
    const float* WqL = (const float*)d_in[13]; const float* bqL = (const float*)d_in[14];
    const float* WkL = (const float*)d_in[15]; const float* bkL = (const float*)d_in[16];
    const float* WvL = (const float*)d_in[17]; const float* bvL = (const float*)d_in[18];
    const float* WeL = (const float*)d_in[19];
    const float* WsL = (const float*)d_in[20]; const float* bsL = (const float*)d_in[21];
    const float* W1  = (const float*)d_in[22]; const float* b1  = (const float*)d_in[23];
    const float* Wc  = (const float*)d_in[24]; const float* bc  = (const float*)d_in[25];
    const float* Wf  = (const float*)d_in[26]; const float* bf  = (const float*)d_in[27];
    float* outp = (float*)d_out;

    // workspace carve
    char* ws = (char*)d_ws;
    size_t off = 0;
    auto carve = [&](size_t bytes) {
        char* p = ws + off;
        off = (off + bytes + 255) & ~(size_t)255;
        return p;
    };
    int* rp    = (int*)carve((NN + 1) * sizeof(int));
    int* cur   = (int*)carve((size_t)NN * sizeof(int));   // doubles as degree histogram
    int* part  = (int*)carve(512 * sizeof(int));
    int* offs  = (int*)carve(512 * sizeof(int));
    int* ssrc  = (int*)carve((size_t)EE * sizeof(int));
    int* seid  = (int*)carve((size_t)EE * sizeof(int));
    float* bigA = (float*)carve((size_t)NN * 256 * sizeof(float)); // Q|K|V|BASE -> g1 -> g3
    float* bigB = (float*)carve((size_t)NN * 256 * sizeof(float)); // h0|hs0|hs1|hs2 -> g2
    float* pl   = (float*)carve((size_t)NMG * 64 * sizeof(float));
    // optional CSR-ordered edge_attr copy (+102.4 MB) — use only if ws allows
    const size_t EAC_BYTES = (size_t)EE * 16 * sizeof(float);
    bool use_eac = (off + EAC_BYTES) <= ws_size;           // runtime-constant -> graph-safe
    float* eac = use_eac ? (float*)carve(EAC_BYTES) : nullptr;

    float* Q    = bigA;
    float* Km   = bigA + (size_t)NN * 64;
    float* V    = bigA + (size_t)NN * 128;
    float* BASE = bigA + (size_t)NN * 192;
    float* h0   = bigB;
    float* hA   = bigB + (size_t)NN * 64;
    float* hB   = bigB + (size_t)NN * 128;
    float* hC   = bigB + (size_t)NN * 192;
    float* g1 = bigA;
    float* g2 = bigB;
    float* g3 = bigA;

    const int* esrc = ei;
    const int* edst = ei + EE;

    // ---- CSR build (once; reused by all 4 layers)
    hipMemsetAsync(cur, 0, (size_t)NN * sizeof(int), stream);
    tf_hist<<<EE / 256, 256, 0, stream>>>(edst, cur);
    tf_scan1<<<391, 256, 0, stream>>>(cur, rp, part);
    tf_scan2<<<1, 512, 0, stream>>>(part, offs, 391);
    tf_scan3<<<392, 256, 0, stream>>>(rp, offs);
    hipMemsetAsync(cur, 0, (size_t)NN * sizeof(int), stream);
    tf_scatter<<<EE / 256, 256, 0, stream>>>(esrc, edst, rp, cur, ssrc, seid);
    if (use_eac)
        tf_ecopy<<<(EE * 4) / 256, 256, 0, stream>>>(seid, ea, eac);

    const int GB = (NN + 63) / 64;   // 1563 GEMM blocks
    const int AB = NN / 4;           // 25000 agg blocks

    // ---- conv1 (IN=128 -> 64)
    tf_gemm<0><<<GB, 256, 0, stream>>>(x, nullptr, nullptr, nullptr, nullptr, nullptr,
                                       Wq1, Wk1, Wv1, Ws1, bq1, bk1, bv1, bs1,
                                       Q, Km, V, BASE, 128, 0);
    if (use_eac)
        tf_agg<true><<<AB, 256, 0, stream>>>(Q, Km, V, BASE, rp, ssrc, seid, eac, We1, h0);
    else
        tf_agg<false><<<AB, 256, 0, stream>>>(Q, Km, V, BASE, rp, ssrc, seid, ea, We1, h0);

    // ---- stacked convs (64 -> 64), outputs kept for classifier concat
    const float* hin = h0;
    float* houts[3] = {hA, hB, hC};
    for (int l = 0; l < 3; ++l) {
        tf_gemm<0><<<GB, 256, 0, stream>>>(hin, nullptr, nullptr, nullptr, nullptr, nullptr,
                                           WqL + l * 4096, WkL + l * 4096, WvL + l * 4096, WsL + l * 4096,
                                           bqL + l * 64, bkL + l * 64, bvL + l * 64, bsL + l * 64,
                                           Q, Km, V, BASE, 64, 0);
        if (use_eac)
            tf_agg<true><<<AB, 256, 0, stream>>>(Q, Km, V, BASE, rp, ssrc, seid, eac,
                                                 WeL + l * 1024, houts[l]);
        else
            tf_agg<false><<<AB, 256, 0, stream>>>(Q, Km, V, BASE, rp, ssrc, seid, ea,
                                                  WeL + l * 1024, houts[l]);
        hin = houts[l];
    }

    // ---- global_add_pool on final h (hC)
    hipMemsetAsync(pl, 0, (size_t)NMG * 64 * sizeof(float), stream);
    tf_pool<<<AB, 256, 0, stream>>>(hC, bat, pl);

    // ---- classifier
    tf_gemm<1><<<GB, 256, 0, stream>>>(nullptr, hA, hB, hC, pl, bat,
                                       W1, nullptr, nullptr, nullptr,
                                       b1, nullptr, nullptr, nullptr,
                                       g1, nullptr, nullptr, nullptr, 256, 0);
    tf_gemm<2><<<GB, 256, 0, stream>>>(g1, nullptr, nullptr, nullptr, nullptr, nullptr,
                                       Wc, nullptr, nullptr, nullptr,
                                       bc, nullptr, nullptr, nullptr,
                                       g2, nullptr, nullptr, nullptr, 256, 1);
    tf_gemm<2><<<GB, 256, 0, stream>>>(g2, nullptr, nullptr, nullptr, nullptr, nullptr,
                                       Wc + 65536, nullptr, nullptr, nullptr,
                                       bc + 256, nullptr, nullptr, nullptr,
                                       g3, nullptr, nullptr, nullptr, 256, 1);
    tf_final<<<AB, 256, 0, stream>>>(g3, Wf, bf, outp);
}

// Round 10
// 2033.162 us; speedup vs baseline: 1.3295x; 1.1684x over previous
//
#include <hip/hip_runtime.h>
#include <cstdint>
#include <cstddef>

// Problem constants (from reference setup_inputs)
#define NN 100000
#define EE 1600000
#define NMG 4000
// leaky_relu negative_slope = 0.01 (jax.nn.leaky_relu default)

// ---------------------------------------------------------------------------
// CSR build: histogram -> exclusive scan -> scatter (edge_index reused by all
// 4 conv layers; built once per call)
// ---------------------------------------------------------------------------
__global__ __launch_bounds__(256) void tf_hist(const int* __restrict__ dst, int* __restrict__ deg) {
    int j = blockIdx.x * 256 + threadIdx.x;
    if (j < EE) atomicAdd(&deg[dst[j]], 1);
}

__global__ __launch_bounds__(256) void tf_scan1(const int* __restrict__ deg, int* __restrict__ rp,
                                                int* __restrict__ part) {
    __shared__ int sm[256];
    int tid = threadIdx.x;
    int i = blockIdx.x * 256 + tid;
    int v = (i < NN) ? deg[i] : 0;
    sm[tid] = v;
    __syncthreads();
    for (int off = 1; off < 256; off <<= 1) {
        int t = (tid >= off) ? sm[tid - off] : 0;
        __syncthreads();
        sm[tid] += t;
        __syncthreads();
    }
    if (i < NN) rp[i] = sm[tid] - v;           // block-local exclusive
    if (tid == 255) part[blockIdx.x] = sm[255]; // block total
}

__global__ __launch_bounds__(512) void tf_scan2(const int* __restrict__ part, int* __restrict__ offs, int nb) {
    __shared__ int sm[512];
    int tid = threadIdx.x;
    int v = (tid < nb) ? part[tid] : 0;
    sm[tid] = v;
    __syncthreads();
    for (int off = 1; off < 512; off <<= 1) {
        int t = (tid >= off) ? sm[tid - off] : 0;
        __syncthreads();
        sm[tid] += t;
        __syncthreads();
    }
    if (tid < nb) offs[tid] = sm[tid] - v;      // exclusive
}

__global__ __launch_bounds__(256) void tf_scan3(int* __restrict__ rp, const int* __restrict__ offs) {
    int i = blockIdx.x * 256 + threadIdx.x;
    if (i < NN) rp[i] += offs[i >> 8];
    else if (i == NN) rp[NN] = EE;
}

__global__ __launch_bounds__(256) void tf_scatter(const int* __restrict__ src, const int* __restrict__ dst,
                                                  const int* __restrict__ rp, int* __restrict__ cur,
                                                  int* __restrict__ ssrc, int* __restrict__ seid) {
    int j = blockIdx.x * 256 + threadIdx.x;
    if (j >= EE) return;
    int d = dst[j];
    int pos = atomicAdd(&cur[d], 1);
    int slot = rp[d] + pos;
    ssrc[slot] = src[j];
    seid[slot] = j;
}

// Reorder edge_attr into CSR slot order (sequential reads in tf_agg).
__global__ __launch_bounds__(256) void tf_ecopy(const int* __restrict__ seid, const float* __restrict__ ea,
                                                float* __restrict__ eac) {
    size_t idx = (size_t)blockIdx.x * 256 + threadIdx.x;   // over EE*4 float4s
    if (idx >= (size_t)EE * 4) return;
    size_t slot = idx >> 2;
    int c4 = (int)(idx & 3);
    const float4* srcp = (const float4*)(ea + (size_t)seid[slot] * 16);
    ((float4*)(eac + slot * 16))[c4] = srcp[c4];
}

// ---------------------------------------------------------------------------
// f32 GEMM, tile: 64 rows x 256 cols, BK=16; 256 threads, 4x16 micro-tile.
// Column ownership: thread tx owns cols {tx*4 + 64g : g=0..3} (4-contig x 4
// strided-by-64). Bs b128 reads then spread 64 lanes over all 32 banks
// (2-way alias = free) instead of 8-way conflicts at tx*16 contiguous.
// acc[j][4g+c] = col (tx*4 + c + 64g) of output row (ty*4+j).
// MODE 0: conv projections -> 4 weight mats [K,64]; group g = output matrix g
// MODE 1: classifier-1, A gathered as concat(hs0|hs1|hs2|pool[batch]) (K=256)
// MODE 2: plain [N,256] @ [256,256] with optional leaky epilogue
// ---------------------------------------------------------------------------
template <int MODE>
__global__ __launch_bounds__(256) void tf_gemm(
    const float* __restrict__ A,
    const float* __restrict__ hs0, const float* __restrict__ hs1,
    const float* __restrict__ hs2, const float* __restrict__ pl,
    const int* __restrict__ batch,
    const float* __restrict__ W0, const float* __restrict__ W1p,
    const float* __restrict__ W2, const float* __restrict__ W3,
    const float* __restrict__ b0, const float* __restrict__ b1p,
    const float* __restrict__ b2, const float* __restrict__ b3,
    float* __restrict__ O0, float* __restrict__ O1,
    float* __restrict__ O2, float* __restrict__ O3,
    int Kdim, int act) {
    __shared__ float As[64][17];   // +1 pad breaks bank aliasing on column reads
    __shared__ float Bs[16][256];
    int tid = threadIdx.x;
    int tx = tid & 15, ty = tid >> 4;
    int bm = blockIdx.x * 64;
    int tx4 = tx * 4;
    float acc[4][16];
#pragma unroll
    for (int j = 0; j < 4; ++j)
#pragma unroll
        for (int i = 0; i < 16; ++i) acc[j][i] = 0.f;

    int arow = tid >> 2;        // 0..63
    int aq = (tid & 3) * 4;     // 0,4,8,12
    int grow = bm + arow;

    for (int k0 = 0; k0 < Kdim; k0 += 16) {
        // ---- A tile (64x16), one float4 per thread
        float4 av = make_float4(0.f, 0.f, 0.f, 0.f);
        if (grow < NN) {
            if (MODE == 1) {
                int k = k0 + aq, g = k >> 6, c = k & 63;
                if (g == 3) av = *(const float4*)(pl + (size_t)batch[grow] * 64 + c);
                else {
                    const float* s = (g == 0) ? hs0 : (g == 1) ? hs1 : hs2;
                    av = *(const float4*)(s + (size_t)grow * 64 + c);
                }
            } else {
                av = *(const float4*)(A + (size_t)grow * Kdim + k0 + aq);
            }
        }
        As[arow][aq + 0] = av.x; As[arow][aq + 1] = av.y;
        As[arow][aq + 2] = av.z; As[arow][aq + 3] = av.w;
        // ---- B tile (16x256), 4 float4 per thread (contiguous row writes)
#pragma unroll
        for (int r = 0; r < 4; ++r) {
            int f4 = tid + r * 256;       // 0..1023
            int t = f4 >> 6;              // 0..15
            int col = (f4 & 63) * 4;      // 0..252
            float4 bv;
            if (MODE == 0) {
                int g = col >> 6, c = col & 63;
                const float* Wg = (g == 0) ? W0 : (g == 1) ? W1p : (g == 2) ? W2 : W3;
                bv = *(const float4*)(Wg + (size_t)(k0 + t) * 64 + c);
            } else {
                bv = *(const float4*)(W0 + (size_t)(k0 + t) * 256 + col);
            }
            *(float4*)&Bs[t][col] = bv;
        }
        __syncthreads();
#pragma unroll
        for (int t = 0; t < 16; ++t) {
            float a0 = As[ty * 4 + 0][t], a1 = As[ty * 4 + 1][t];
            float a2 = As[ty * 4 + 2][t], a3 = As[ty * 4 + 3][t];
            float4 v0 = *(const float4*)&Bs[t][tx4 + 0];
            float4 v1 = *(const float4*)&Bs[t][tx4 + 64];
            float4 v2 = *(const float4*)&Bs[t][tx4 + 128];
            float4 v3 = *(const float4*)&Bs[t][tx4 + 192];
            float bb[16] = {v0.x, v0.y, v0.z, v0.w, v1.x, v1.y, v1.z, v1.w,
                            v2.x, v2.y, v2.z, v2.w, v3.x, v3.y, v3.z, v3.w};
#pragma unroll
            for (int i = 0; i < 16; ++i) {
                acc[0][i] = fmaf(a0, bb[i], acc[0][i]);
                acc[1][i] = fmaf(a1, bb[i], acc[1][i]);
                acc[2][i] = fmaf(a2, bb[i], acc[2][i]);
                acc[3][i] = fmaf(a3, bb[i], acc[3][i]);
            }
        }
        __syncthreads();
    }
    // ---- epilogue
    if (MODE == 0) {
        // group g = output matrix g; this thread's cols in it: tx*4..tx*4+3
#pragma unroll
        for (int g = 0; g < 4; ++g) {
            const float* bias = (g == 0) ? b0 : (g == 1) ? b1p : (g == 2) ? b2 : b3;
            float* Out = (g == 0) ? O0 : (g == 1) ? O1 : (g == 2) ? O2 : O3;
            float4 bv = *(const float4*)(bias + tx4);
#pragma unroll
            for (int j = 0; j < 4; ++j) {
                int r = bm + ty * 4 + j;
                if (r < NN) {
                    float4 v;
                    v.x = acc[j][g * 4 + 0] + bv.x;
                    v.y = acc[j][g * 4 + 1] + bv.y;
                    v.z = acc[j][g * 4 + 2] + bv.z;
                    v.w = acc[j][g * 4 + 3] + bv.w;
                    *(float4*)(Out + (size_t)r * 64 + tx4) = v;
                }
            }
        }
    } else {
#pragma unroll
        for (int j = 0; j < 4; ++j) {
            int r = bm + ty * 4 + j;
            if (r < NN) {
#pragma unroll
                for (int g = 0; g < 4; ++g) {
                    int col = tx4 + g * 64;
                    float4 v;
                    v.x = acc[j][g * 4 + 0] + b0[col + 0];
                    v.y = acc[j][g * 4 + 1] + b0[col + 1];
                    v.z = acc[j][g * 4 + 2] + b0[col + 2];
                    v.w = acc[j][g * 4 + 3] + b0[col + 3];
                    if (act) {
                        v.x = v.x > 0.f ? v.x : 0.01f * v.x;
                        v.y = v.y > 0.f ? v.y : 0.01f * v.y;
                        v.z = v.z > 0.f ? v.z : 0.01f * v.z;
                        v.w = v.w > 0.f ? v.w : 0.01f * v.w;
                    }
                    *(float4*)(O0 + (size_t)r * 256 + col) = v;
                }
            }
        }
    }
}

// ---------------------------------------------------------------------------
// Edge attention aggregation, one wave per dst node, lane = channel.
//   alpha_j = (q.k[sj] + ea_j.qe)/8  where qe = We @ q (16-dim, computed once)
//   out_e   = (sum_j p_j ea_j) @ We  (16-wide pea accumulator, applied once)
// Two independent online-softmax streams (even/odd edges), merged at end.
// USE_EAC: read edge_attr in sequential CSR order (eac) vs random via seid.
// ---------------------------------------------------------------------------
template <bool USE_EAC>
__global__ __launch_bounds__(256) void tf_agg(
    const float* __restrict__ Q, const float* __restrict__ Km,
    const float* __restrict__ V, const float* __restrict__ BASE,
    const int* __restrict__ rp, const int* __restrict__ ssrc, const int* __restrict__ seid,
    const float* __restrict__ eaw,   // USE_EAC ? eac[EE,16] (slot order) : ea[EE,16] (orig order)
    const float* __restrict__ We,    // [16,64]
    float* __restrict__ out) {
    __shared__ float qsm[4][64];
    int wv = threadIdx.x >> 6;
    int node = (blockIdx.x << 2) + wv;
    int lane = threadIdx.x & 63;
    if (node >= NN) return;

    float w[16];
#pragma unroll
    for (int d = 0; d < 16; ++d) w[d] = We[d * 64 + lane];

    float q = Q[(size_t)node * 64 + lane];

    // ---- qe_d = sum_c We[d][c] * q[c], d = 0..15 (LDS transpose + 4-lane reduce)
    qsm[wv][lane] = q;
    int dgrp = lane >> 2;          // 16 d-groups x 4 lanes
    int cb = lane & 3;
    float pq = 0.f;
#pragma unroll
    for (int k2 = 0; k2 < 16; ++k2) {
        int c = cb + (k2 << 2);
        pq = fmaf(qsm[wv][c], We[dgrp * 64 + c], pq);
    }
    pq += __shfl_xor(pq, 1);
    pq += __shfl_xor(pq, 2);                      // all 4 lanes of group d hold qe_d
    float qel = __shfl(pq, (lane & 15) << 2);     // lane<16 -> qe[lane]

    int beg = rp[node], end = rp[node + 1];
    float mA = -INFINITY, sA = 0.f, accA = 0.f, peaA = 0.f;
    float mB = -INFINITY, sB = 0.f, accB = 0.f, peaB = 0.f;

    int it = beg;
    for (; it + 1 < end; it += 2) {
        int sa = ssrc[it], sb = ssrc[it + 1];
        float ea_a, ea_b;
        if (USE_EAC) {
            ea_a = (lane < 16) ? eaw[(size_t)it * 16 + lane] : 0.f;
            ea_b = (lane < 16) ? eaw[(size_t)(it + 1) * 16 + lane] : 0.f;
        } else {
            int ja = seid[it], jb = seid[it + 1];
            ea_a = (lane < 16) ? eaw[(size_t)ja * 16 + lane] : 0.f;
            ea_b = (lane < 16) ? eaw[(size_t)jb * 16 + lane] : 0.f;
        }
        float ka = Km[(size_t)sa * 64 + lane];
        float kb = Km[(size_t)sb * 64 + lane];
        float va = V[(size_t)sa * 64 + lane];
        float vb = V[(size_t)sb * 64 + lane];
        float pa = fmaf(q, ka, ea_a * qel);
        float pb = fmaf(q, kb, ea_b * qel);
#pragma unroll
        for (int o = 32; o; o >>= 1) {
            pa += __shfl_xor(pa, o);
            pb += __shfl_xor(pb, o);
        }
        float alA = pa * 0.125f, alB = pb * 0.125f;   // 1/sqrt(64)
        float nmA = fmaxf(mA, alA);
        float scA = __expf(mA - nmA);
        float ppA = __expf(alA - nmA);
        sA = sA * scA + ppA;
        accA = fmaf(ppA, va, accA * scA);
        peaA = fmaf(ppA, ea_a, peaA * scA);
        mA = nmA;
        float nmB = fmaxf(mB, alB);
        float scB = __expf(mB - nmB);
        float ppB = __expf(alB - nmB);
        sB = sB * scB + ppB;
        accB = fmaf(ppB, vb, accB * scB);
        peaB = fmaf(ppB, ea_b, peaB * scB);
        mB = nmB;
    }
    if (it < end) {   // odd tail -> stream A
        int sa = ssrc[it];
        float ea_a;
        if (USE_EAC) ea_a = (lane < 16) ? eaw[(size_t)it * 16 + lane] : 0.f;
        else {
            int ja = seid[it];
            ea_a = (lane < 16) ? eaw[(size_t)ja * 16 + lane] : 0.f;
        }
        float ka = Km[(size_t)sa * 64 + lane];
        float va = V[(size_t)sa * 64 + lane];
        float pa = fmaf(q, ka, ea_a * qel);
#pragma unroll
        for (int o = 32; o; o >>= 1) pa += __shfl_xor(pa, o);
        float alA = pa * 0.125f;
        float nmA = fmaxf(mA, alA);
        float scA = __expf(mA - nmA);
        float ppA = __expf(alA - nmA);
        sA = sA * scA + ppA;
        accA = fmaf(ppA, va, accA * scA);
        peaA = fmaf(ppA, ea_a, peaA * scA);
        mA = nmA;
    }

    float base = BASE[(size_t)node * 64 + lane];
    float o;
    if (end > beg) {
        float m = fmaxf(mA, mB);      // finite: stream A always has >=1 edge
        float cA = __expf(mA - m);
        float cB = __expf(mB - m);    // mB may be -inf -> 0
        float s = sA * cA + sB * cB;
        float acc = accA * cA + accB * cB;
        float pea = peaA * cA + peaB * cB;
        float eaout = 0.f;
#pragma unroll
        for (int d = 0; d < 16; ++d) eaout = fmaf(__shfl(pea, d), w[d], eaout);
        o = (acc + eaout) / (s + 1e-16f) + base;
    } else {
        o = base;                     // empty segment: softmax contributes 0
    }
    out[(size_t)node * 64 + lane] = (o > 0.f) ? o : 0.01f * o;
}

// global_add_pool via atomics (batch sorted)
__global__ __launch_bounds__(256) void tf_pool(const float* __restrict__ h, const int* __restrict__ bat,
                                               float* __restrict__ pl) {
    int idx = blockIdx.x * 256 + threadIdx.x;   // exactly N*64
    if (idx >= NN * 64) return;
    int node = idx >> 6, l = idx & 63;
    atomicAdd(&pl[(size_t)bat[node] * 64 + l], h[idx]);
}

// final row-dot (256) + sigmoid; one wave per node
__global__ __launch_bounds__(256) void tf_final(const float* __restrict__ g, const float* __restrict__ Wf,
                                                const float* __restrict__ bf, float* __restrict__ out) {
    int wid = (blockIdx.x * 256 + threadIdx.x) >> 6;
    int lane = threadIdx.x & 63;
    if (wid >= NN) return;
    const float* row = g + (size_t)wid * 256;
    float s = row[lane] * Wf[lane] + row[lane + 64] * Wf[lane + 64] +
              row[lane + 128] * Wf[lane + 128] + row[lane + 192] * Wf[lane + 192];
#pragma unroll
    for (int off = 32; off; off >>= 1) s += __shfl_xor(s, off);
    if (lane == 0) out[wid] = 1.f / (1.f + __expf(-(s + bf[0])));
}

// ---------------------------------------------------------------------------
extern "C" void kernel_launch(void* const* d_in, const int* in_sizes, int n_in,
                              void* d_out, int out_size, void* d_ws, size_t ws_size,
                              hipStream_t stream) {
    (void)in_sizes; (void)n_in; (void)out_size;
    const float* x   = (const float*)d_in[0];
    const int*   ei  = (const int*)d_in[1];
    const float* ea  = (const float*)d_in[2];
    const int*   bat = (const int*)d_in[3];
    const float* Wq1 = (const float*)d_in[4];  const float* bq1 = (const float*)d_in[5];
    const float* Wk1 = (const float*)d_in[6];  const float* bk1 = (const float*)d_in[7];
    const float* Wv1 = (const float*)d_in[8];  const float* bv1 = (const float*)d_in[9];
    const float* We1 = (const float*)d_in[10];
    const float* Ws1 = (const float*)d_in[11]; const float* bs1 = (const float*)d_in[12];
    const float* WqL = (const float*)d_in[13]; const float* bqL = (const float*)d_in[14];
    const float* WkL = (const float*)d_in[15]; const float* bkL = (const float*)d_in[16];
    const float* WvL = (const float*)d_in[17]; const float* bvL = (const float*)d_in[18];
    const float* WeL = (const float*)d_in[19];
    const float* WsL = (const float*)d_in[20]; const float* bsL = (const float*)d_in[21];
    const float* W1  = (const float*)d_in[22]; const float* b1  = (const float*)d_in[23];
    const float* Wc  = (const float*)d_in[24]; const float* bc  = (const float*)d_in[25];
    const float* Wf  = (const float*)d_in[26]; const float* bf  = (const float*)d_in[27];
    float* outp = (float*)d_out;

    // workspace carve
    char* ws = (char*)d_ws;
    size_t off = 0;
    auto carve = [&](size_t bytes) {
        char* p = ws + off;
        off = (off + bytes + 255) & ~(size_t)255;
        return p;
    };
    int* rp    = (int*)carve((NN + 1) * sizeof(int));
    int* cur   = (int*)carve((size_t)NN * sizeof(int));   // doubles as degree histogram
    int* part  = (int*)carve(512 * sizeof(int));
    int* offs  = (int*)carve(512 * sizeof(int));
    int* ssrc  = (int*)carve((size_t)EE * sizeof(int));
    int* seid  = (int*)carve((size_t)EE * sizeof(int));
    float* bigA = (float*)carve((size_t)NN * 256 * sizeof(float)); // Q|K|V|BASE -> g1 -> g3
    float* bigB = (float*)carve((size_t)NN * 256 * sizeof(float)); // h0|hs0|hs1|hs2 -> g2
    float* pl   = (float*)carve((size_t)NMG * 64 * sizeof(float));
    // optional CSR-ordered edge_attr copy (+102.4 MB) — use only if ws allows
    const size_t EAC_BYTES = (size_t)EE * 16 * sizeof(float);
    bool use_eac = (off + EAC_BYTES) <= ws_size;           // runtime-constant -> graph-safe
    float* eac = use_eac ? (float*)carve(EAC_BYTES) : nullptr;

    float* Q    = bigA;
    float* Km   = bigA + (size_t)NN * 64;
    float* V    = bigA + (size_t)NN * 128;
    float* BASE = bigA + (size_t)NN * 192;
    float* h0   = bigB;
    float* hA   = bigB + (size_t)NN * 64;
    float* hB   = bigB + (size_t)NN * 128;
    float* hC   = bigB + (size_t)NN * 192;
    float* g1 = bigA;
    float* g2 = bigB;
    float* g3 = bigA;

    const int* esrc = ei;
    const int* edst = ei + EE;

    // ---- CSR build (once; reused by all 4 layers)
    hipMemsetAsync(cur, 0, (size_t)NN * sizeof(int), stream);
    tf_hist<<<EE / 256, 256, 0, stream>>>(edst, cur);
    tf_scan1<<<391, 256, 0, stream>>>(cur, rp, part);
    tf_scan2<<<1, 512, 0, stream>>>(part, offs, 391);
    tf_scan3<<<392, 256, 0, stream>>>(rp, offs);
    hipMemsetAsync(cur, 0, (size_t)NN * sizeof(int), stream);
    tf_scatter<<<EE / 256, 256, 0, stream>>>(esrc, edst, rp, cur, ssrc, seid);
    if (use_eac)
        tf_ecopy<<<(EE * 4) / 256, 256, 0, stream>>>(seid, ea, eac);

    const int GB = (NN + 63) / 64;   // 1563 GEMM blocks
    const int AB = NN / 4;           // 25000 agg blocks

    // ---- conv1 (IN=128 -> 64)
    tf_gemm<0><<<GB, 256, 0, stream>>>(x, nullptr, nullptr, nullptr, nullptr, nullptr,
                                       Wq1, Wk1, Wv1, Ws1, bq1, bk1, bv1, bs1,
                                       Q, Km, V, BASE, 128, 0);
    if (use_eac)
        tf_agg<true><<<AB, 256, 0, stream>>>(Q, Km, V, BASE, rp, ssrc, seid, eac, We1, h0);
    else
        tf_agg<false><<<AB, 256, 0, stream>>>(Q, Km, V, BASE, rp, ssrc, seid, ea, We1, h0);

    // ---- stacked convs (64 -> 64), outputs kept for classifier concat
    const float* hin = h0;
    float* houts[3] = {hA, hB, hC};
    for (int l = 0; l < 3; ++l) {
        tf_gemm<0><<<GB, 256, 0, stream>>>(hin, nullptr, nullptr, nullptr, nullptr, nullptr,
                                           WqL + l * 4096, WkL + l * 4096, WvL + l * 4096, WsL + l * 4096,
                                           bqL + l * 64, bkL + l * 64, bvL + l * 64, bsL + l * 64,
                                           Q, Km, V, BASE, 64, 0);
        if (use_eac)
            tf_agg<true><<<AB, 256, 0, stream>>>(Q, Km, V, BASE, rp, ssrc, seid, eac,
                                                 WeL + l * 1024, houts[l]);
        else
            tf_agg<false><<<AB, 256, 0, stream>>>(Q, Km, V, BASE, rp, ssrc, seid, ea,
                                                  WeL + l * 1024, houts[l]);
        hin = houts[l];
    }

    // ---- global_add_pool on final h (hC)
    hipMemsetAsync(pl, 0, (size_t)NMG * 64 * sizeof(float), stream);
    tf_pool<<<AB, 256, 0, stream>>>(hC, bat, pl);

    // ---- classifier
    tf_gemm<1><<<GB, 256, 0, stream>>>(nullptr, hA, hB, hC, pl, bat,
                                       W1, nullptr, nullptr, nullptr,
                                       b1, nullptr, nullptr, nullptr,
                                       g1, nullptr, nullptr, nullptr, 256, 0);
    tf_gemm<2><<<GB, 256, 0, stream>>>(g1, nullptr, nullptr, nullptr, nullptr, nullptr,
                                       Wc, nullptr, nullptr, nullptr,
                                       bc, nullptr, nullptr, nullptr,
                                       g2, nullptr, nullptr, nullptr, 256, 1);
    tf_gemm<2><<<GB, 256, 0, stream>>>(g2, nullptr, nullptr, nullptr, nullptr, nullptr,
                                       Wc + 65536, nullptr, nullptr, nullptr,
                                       bc + 256, nullptr, nullptr, nullptr,
                                       g3, nullptr, nullptr, nullptr, 256, 1);
    tf_final<<<AB, 256, 0, stream>>>(g3, Wf, bf, outp);
}

// Round 13
// 1868.887 us; speedup vs baseline: 1.4464x; 1.0879x over previous
//
#include <hip/hip_runtime.h>
#include <cstdint>
#include <cstddef>

// Problem constants (from reference setup_inputs)
#define NN 100000
#define EE 1600000
#define NMG 4000
// leaky_relu negative_slope = 0.01 (jax.nn.leaky_relu default)

// ---------------------------------------------------------------------------
// CSR build: histogram -> exclusive scan -> scatter (edge_index reused by all
// 4 conv layers; built once per call)
// ---------------------------------------------------------------------------
__global__ __launch_bounds__(256) void tf_hist(const int* __restrict__ dst, int* __restrict__ deg) {
    int j = blockIdx.x * 256 + threadIdx.x;
    if (j < EE) atomicAdd(&deg[dst[j]], 1);
}

__global__ __launch_bounds__(256) void tf_scan1(const int* __restrict__ deg, int* __restrict__ rp,
                                                int* __restrict__ part) {
    __shared__ int sm[256];
    int tid = threadIdx.x;
    int i = blockIdx.x * 256 + tid;
    int v = (i < NN) ? deg[i] : 0;
    sm[tid] = v;
    __syncthreads();
    for (int off = 1; off < 256; off <<= 1) {
        int t = (tid >= off) ? sm[tid - off] : 0;
        __syncthreads();
        sm[tid] += t;
        __syncthreads();
    }
    if (i < NN) rp[i] = sm[tid] - v;           // block-local exclusive
    if (tid == 255) part[blockIdx.x] = sm[255]; // block total
}

__global__ __launch_bounds__(512) void tf_scan2(const int* __restrict__ part, int* __restrict__ offs, int nb) {
    __shared__ int sm[512];
    int tid = threadIdx.x;
    int v = (tid < nb) ? part[tid] : 0;
    sm[tid] = v;
    __syncthreads();
    for (int off = 1; off < 512; off <<= 1) {
        int t = (tid >= off) ? sm[tid - off] : 0;
        __syncthreads();
        sm[tid] += t;
        __syncthreads();
    }
    if (tid < nb) offs[tid] = sm[tid] - v;      // exclusive
}

__global__ __launch_bounds__(256) void tf_scan3(int* __restrict__ rp, const int* __restrict__ offs) {
    int i = blockIdx.x * 256 + threadIdx.x;
    if (i < NN) rp[i] += offs[i >> 8];
    else if (i == NN) rp[NN] = EE;
}

__global__ __launch_bounds__(256) void tf_scatter(const int* __restrict__ src, const int* __restrict__ dst,
                                                  const int* __restrict__ rp, int* __restrict__ cur,
                                                  int* __restrict__ ssrc, int* __restrict__ seid) {
    int j = blockIdx.x * 256 + threadIdx.x;
    if (j >= EE) return;
    int d = dst[j];
    int pos = atomicAdd(&cur[d], 1);
    int slot = rp[d] + pos;
    ssrc[slot] = src[j];
    seid[slot] = j;
}

// Reorder edge_attr into CSR slot order (sequential reads in tf_agg).
__global__ __launch_bounds__(256) void tf_ecopy(const int* __restrict__ seid, const float* __restrict__ ea,
                                                float* __restrict__ eac) {
    size_t idx = (size_t)blockIdx.x * 256 + threadIdx.x;   // over EE*4 float4s
    if (idx >= (size_t)EE * 4) return;
    size_t slot = idx >> 2;
    int c4 = (int)(idx & 3);
    const float4* srcp = (const float4*)(ea + (size_t)seid[slot] * 16);
    ((float4*)(eac + slot * 16))[c4] = srcp[c4];
}

// ---------------------------------------------------------------------------
// f32 GEMM, tile: 64 rows x 256 cols, BK=16; 256 threads, 4x16 micro-tile.
// Column ownership: thread tx owns cols {tx*4 + 64g : g=0..3} -> Bs b128 reads
// spread 64 lanes over all 32 banks (2-way alias = free).
// MODE 0: conv projections -> 4 weight mats [K,64]; group g = output matrix g
// MODE 1: classifier-1, A gathered as concat(hs0|hs1|hs2|pool[batch]) (K=256)
// MODE 2: plain [N,256] @ [256,256] with optional leaky epilogue
// ---------------------------------------------------------------------------
template <int MODE>
__global__ __launch_bounds__(256) void tf_gemm(
    const float* __restrict__ A,
    const float* __restrict__ hs0, const float* __restrict__ hs1,
    const float* __restrict__ hs2, const float* __restrict__ pl,
    const int* __restrict__ batch,
    const float* __restrict__ W0, const float* __restrict__ W1p,
    const float* __restrict__ W2, const float* __restrict__ W3,
    const float* __restrict__ b0, const float* __restrict__ b1p,
    const float* __restrict__ b2, const float* __restrict__ b3,
    float* __restrict__ O0, float* __restrict__ O1,
    float* __restrict__ O2, float* __restrict__ O3,
    int Kdim, int act) {
    __shared__ float As[64][17];   // +1 pad breaks bank aliasing on column reads
    __shared__ float Bs[16][256];
    int tid = threadIdx.x;
    int tx = tid & 15, ty = tid >> 4;
    int bm = blockIdx.x * 64;
    int tx4 = tx * 4;
    float acc[4][16];
#pragma unroll
    for (int j = 0; j < 4; ++j)
#pragma unroll
        for (int i = 0; i < 16; ++i) acc[j][i] = 0.f;

    int arow = tid >> 2;        // 0..63
    int aq = (tid & 3) * 4;     // 0,4,8,12
    int grow = bm + arow;

    for (int k0 = 0; k0 < Kdim; k0 += 16) {
        // ---- A tile (64x16), one float4 per thread
        float4 av = make_float4(0.f, 0.f, 0.f, 0.f);
        if (grow < NN) {
            if (MODE == 1) {
                int k = k0 + aq, g = k >> 6, c = k & 63;
                if (g == 3) av = *(const float4*)(pl + (size_t)batch[grow] * 64 + c);
                else {
                    const float* s = (g == 0) ? hs0 : (g == 1) ? hs1 : hs2;
                    av = *(const float4*)(s + (size_t)grow * 64 + c);
                }
            } else {
                av = *(const float4*)(A + (size_t)grow * Kdim + k0 + aq);
            }
        }
        As[arow][aq + 0] = av.x; As[arow][aq + 1] = av.y;
        As[arow][aq + 2] = av.z; As[arow][aq + 3] = av.w;
        // ---- B tile (16x256), 4 float4 per thread (contiguous row writes)
#pragma unroll
        for (int r = 0; r < 4; ++r) {
            int f4 = tid + r * 256;       // 0..1023
            int t = f4 >> 6;              // 0..15
            int col = (f4 & 63) * 4;      // 0..252
            float4 bv;
            if (MODE == 0) {
                int g = col >> 6, c = col & 63;
                const float* Wg = (g == 0) ? W0 : (g == 1) ? W1p : (g == 2) ? W2 : W3;
                bv = *(const float4*)(Wg + (size_t)(k0 + t) * 64 + c);
            } else {
                bv = *(const float4*)(W0 + (size_t)(k0 + t) * 256 + col);
            }
            *(float4*)&Bs[t][col] = bv;
        }
        __syncthreads();
#pragma unroll
        for (int t = 0; t < 16; ++t) {
            float a0 = As[ty * 4 + 0][t], a1 = As[ty * 4 + 1][t];
            float a2 = As[ty * 4 + 2][t], a3 = As[ty * 4 + 3][t];
            float4 v0 = *(const float4*)&Bs[t][tx4 + 0];
            float4 v1 = *(const float4*)&Bs[t][tx4 + 64];
            float4 v2 = *(const float4*)&Bs[t][tx4 + 128];
            float4 v3 = *(const float4*)&Bs[t][tx4 + 192];
            float bb[16] = {v0.x, v0.y, v0.z, v0.w, v1.x, v1.y, v1.z, v1.w,
                            v2.x, v2.y, v2.z, v2.w, v3.x, v3.y, v3.z, v3.w};
#pragma unroll
            for (int i = 0; i < 16; ++i) {
                acc[0][i] = fmaf(a0, bb[i], acc[0][i]);
                acc[1][i] = fmaf(a1, bb[i], acc[1][i]);
                acc[2][i] = fmaf(a2, bb[i], acc[2][i]);
                acc[3][i] = fmaf(a3, bb[i], acc[3][i]);
            }
        }
        __syncthreads();
    }
    // ---- epilogue
    if (MODE == 0) {
#pragma unroll
        for (int g = 0; g < 4; ++g) {
            const float* bias = (g == 0) ? b0 : (g == 1) ? b1p : (g == 2) ? b2 : b3;
            float* Out = (g == 0) ? O0 : (g == 1) ? O1 : (g == 2) ? O2 : O3;
            float4 bv = *(const float4*)(bias + tx4);
#pragma unroll
            for (int j = 0; j < 4; ++j) {
                int r = bm + ty * 4 + j;
                if (r < NN) {
                    float4 v;
                    v.x = acc[j][g * 4 + 0] + bv.x;
                    v.y = acc[j][g * 4 + 1] + bv.y;
                    v.z = acc[j][g * 4 + 2] + bv.z;
                    v.w = acc[j][g * 4 + 3] + bv.w;
                    *(float4*)(Out + (size_t)r * 64 + tx4) = v;
                }
            }
        }
    } else {
#pragma unroll
        for (int j = 0; j < 4; ++j) {
            int r = bm + ty * 4 + j;
            if (r < NN) {
#pragma unroll
                for (int g = 0; g < 4; ++g) {
                    int col = tx4 + g * 64;
                    float4 v;
                    v.x = acc[j][g * 4 + 0] + b0[col + 0];
                    v.y = acc[j][g * 4 + 1] + b0[col + 1];
                    v.z = acc[j][g * 4 + 2] + b0[col + 2];
                    v.w = acc[j][g * 4 + 3] + b0[col + 3];
                    if (act) {
                        v.x = v.x > 0.f ? v.x : 0.01f * v.x;
                        v.y = v.y > 0.f ? v.y : 0.01f * v.y;
                        v.z = v.z > 0.f ? v.z : 0.01f * v.z;
                        v.w = v.w > 0.f ? v.w : 0.01f * v.w;
                    }
                    *(float4*)(O0 + (size_t)r * 256 + col) = v;
                }
            }
        }
    }
}

// ---------------------------------------------------------------------------
// Edge attention aggregation, one wave per dst node, lane = channel.
//   alpha_j = (q.k[sj] + ea_j.qe)/8  where qe = We @ q (16-dim, computed once)
//   out_e   = (sum_j p_j ea_j) @ We  (16-wide pea accumulator, applied once)
// NO max-subtraction: p_j = exp(alpha_j) directly. Mathematically identical
// after normalization (ref's exp(a-m)/sum is scale-invariant; eps term differs
// by 1e-16*e^-m, negligible). alphas are O(+-50) worst-case -> f32-safe.
// Removes the serial rescale chain -> s/acc/pea are independent FMAs.
// 4x edge unroll: 8 outstanding K/V gathers per wave for latency hiding.
// USE_EAC: read edge_attr in sequential CSR order (eac) vs random via seid.
// ---------------------------------------------------------------------------
template <bool USE_EAC>
__global__ __launch_bounds__(256) void tf_agg(
    const float* __restrict__ Q, const float* __restrict__ Km,
    const float* __restrict__ V, const float* __restrict__ BASE,
    const int* __restrict__ rp, const int* __restrict__ ssrc, const int* __restrict__ seid,
    const float* __restrict__ eaw,   // USE_EAC ? eac[EE,16] (slot order) : ea[EE,16] (orig order)
    const float* __restrict__ We,    // [16,64]
    float* __restrict__ out) {
    __shared__ float qsm[4][64];
    int wv = threadIdx.x >> 6;
    int node = (blockIdx.x << 2) + wv;
    int lane = threadIdx.x & 63;
    if (node >= NN) return;

    float q = Q[(size_t)node * 64 + lane];

    // ---- qe_d = sum_c We[d][c] * q[c], d = 0..15 (LDS transpose + 4-lane reduce)
    qsm[wv][lane] = q;
    int dgrp = lane >> 2;          // 16 d-groups x 4 lanes
    int cb = lane & 3;
    float pq = 0.f;
#pragma unroll
    for (int k2 = 0; k2 < 16; ++k2) {
        int c = cb + (k2 << 2);
        pq = fmaf(qsm[wv][c], We[dgrp * 64 + c], pq);
    }
    pq += __shfl_xor(pq, 1);
    pq += __shfl_xor(pq, 2);                      // all 4 lanes of group d hold qe_d
    float qel = __shfl(pq, (lane & 15) << 2);     // lane<16 -> qe[lane]

    int beg = rp[node], end = rp[node + 1];
    float s = 0.f, acc = 0.f, pea = 0.f;

    int it = beg;
    for (; it + 3 < end; it += 4) {
        int s0 = ssrc[it], s1 = ssrc[it + 1], s2 = ssrc[it + 2], s3 = ssrc[it + 3];
        float ea0, ea1, ea2, ea3;
        if (USE_EAC) {
            ea0 = (lane < 16) ? eaw[(size_t)it * 16 + lane] : 0.f;
            ea1 = (lane < 16) ? eaw[(size_t)(it + 1) * 16 + lane] : 0.f;
            ea2 = (lane < 16) ? eaw[(size_t)(it + 2) * 16 + lane] : 0.f;
            ea3 = (lane < 16) ? eaw[(size_t)(it + 3) * 16 + lane] : 0.f;
        } else {
            int j0 = seid[it], j1 = seid[it + 1], j2 = seid[it + 2], j3 = seid[it + 3];
            ea0 = (lane < 16) ? eaw[(size_t)j0 * 16 + lane] : 0.f;
            ea1 = (lane < 16) ? eaw[(size_t)j1 * 16 + lane] : 0.f;
            ea2 = (lane < 16) ? eaw[(size_t)j2 * 16 + lane] : 0.f;
            ea3 = (lane < 16) ? eaw[(size_t)j3 * 16 + lane] : 0.f;
        }
        float k0 = Km[(size_t)s0 * 64 + lane];
        float k1 = Km[(size_t)s1 * 64 + lane];
        float k2 = Km[(size_t)s2 * 64 + lane];
        float k3 = Km[(size_t)s3 * 64 + lane];
        float v0 = V[(size_t)s0 * 64 + lane];
        float v1 = V[(size_t)s1 * 64 + lane];
        float v2 = V[(size_t)s2 * 64 + lane];
        float v3 = V[(size_t)s3 * 64 + lane];
        float p0 = fmaf(q, k0, ea0 * qel);
        float p1 = fmaf(q, k1, ea1 * qel);
        float p2 = fmaf(q, k2, ea2 * qel);
        float p3 = fmaf(q, k3, ea3 * qel);
#pragma unroll
        for (int o = 32; o; o >>= 1) {
            p0 += __shfl_xor(p0, o);
            p1 += __shfl_xor(p1, o);
            p2 += __shfl_xor(p2, o);
            p3 += __shfl_xor(p3, o);
        }
        float e0 = __expf(p0 * 0.125f);
        float e1 = __expf(p1 * 0.125f);
        float e2 = __expf(p2 * 0.125f);
        float e3 = __expf(p3 * 0.125f);
        s += (e0 + e1) + (e2 + e3);
        acc = fmaf(e0, v0, fmaf(e1, v1, fmaf(e2, v2, fmaf(e3, v3, acc))));
        pea = fmaf(e0, ea0, fmaf(e1, ea1, fmaf(e2, ea2, fmaf(e3, ea3, pea))));
    }
    for (; it < end; ++it) {
        int s0 = ssrc[it];
        float ea0;
        if (USE_EAC) ea0 = (lane < 16) ? eaw[(size_t)it * 16 + lane] : 0.f;
        else {
            int j0 = seid[it];
            ea0 = (lane < 16) ? eaw[(size_t)j0 * 16 + lane] : 0.f;
        }
        float k0 = Km[(size_t)s0 * 64 + lane];
        float v0 = V[(size_t)s0 * 64 + lane];
        float p0 = fmaf(q, k0, ea0 * qel);
#pragma unroll
        for (int o = 32; o; o >>= 1) p0 += __shfl_xor(p0, o);
        float e0 = __expf(p0 * 0.125f);
        s += e0;
        acc = fmaf(e0, v0, acc);
        pea = fmaf(e0, ea0, pea);
    }

    float base = BASE[(size_t)node * 64 + lane];
    float o;
    if (end > beg) {
        float eaout = 0.f;
#pragma unroll
        for (int d = 0; d < 16; ++d) eaout = fmaf(__shfl(pea, d), We[d * 64 + lane], eaout);
        o = (acc + eaout) / (s + 1e-16f) + base;
    } else {
        o = base;                     // empty segment: softmax contributes 0
    }
    out[(size_t)node * 64 + lane] = (o > 0.f) ? o : 0.01f * o;
}

// global_add_pool via atomics (batch sorted)
__global__ __launch_bounds__(256) void tf_pool(const float* __restrict__ h, const int* __restrict__ bat,
                                               float* __restrict__ pl) {
    int idx = blockIdx.x * 256 + threadIdx.x;   // exactly N*64
    if (idx >= NN * 64) return;
    int node = idx >> 6, l = idx & 63;
    atomicAdd(&pl[(size_t)bat[node] * 64 + l], h[idx]);
}

// final row-dot (256) + sigmoid; one wave per node
__global__ __launch_bounds__(256) void tf_final(const float* __restrict__ g, const float* __restrict__ Wf,
                                                const float* __restrict__ bf, float* __restrict__ out) {
    int wid = (blockIdx.x * 256 + threadIdx.x) >> 6;
    int lane = threadIdx.x & 63;
    if (wid >= NN) return;
    const float* row = g + (size_t)wid * 256;
    float s = row[lane] * Wf[lane] + row[lane + 64] * Wf[lane + 64] +
              row[lane + 128] * Wf[lane + 128] + row[lane + 192] * Wf[lane + 192];
#pragma unroll
    for (int off = 32; off; off >>= 1) s += __shfl_xor(s, off);
    if (lane == 0) out[wid] = 1.f / (1.f + __expf(-(s + bf[0])));
}

// ---------------------------------------------------------------------------
extern "C" void kernel_launch(void* const* d_in, const int* in_sizes, int n_in,
                              void* d_out, int out_size, void* d_ws, size_t ws_size,
                              hipStream_t stream) {
    (void)in_sizes; (void)n_in; (void)out_size;
    const float* x   = (const float*)d_in[0];
    const int*   ei  = (const int*)d_in[1];
    const float* ea  = (const float*)d_in[2];
    const int*   bat = (const int*)d_in[3];
    const float* Wq1 = (const float*)d_in[4];  const float* bq1 = (const float*)d_in[5];
    const float* Wk1 = (const float*)d_in[6];  const float* bk1 = (const float*)d_in[7];
    const float* Wv1 = (const float*)d_in[8];  const float* bv1 = (const float*)d_in[9];
    const float* We1 = (const float*)d_in[10];
    const float* Ws1 = (const float*)d_in[11]; const float* bs1 = (const float*)d_in[12];
    const float* WqL = (const float*)d_in[13]; const float* bqL = (const float*)d_in[14];
    const float* WkL = (const float*)d_in[15]; const float* bkL = (const float*)d_in[16];
    const float* WvL = (const float*)d_in[17]; const float* bvL = (const float*)d_in[18];
    const float* WeL = (const float*)d_in[19];
    const float* WsL = (const float*)d_in[20]; const float* bsL = (const float*)d_in[21];
    const float* W1  = (const float*)d_in[22]; const float* b1  = (const float*)d_in[23];
    const float* Wc  = (const float*)d_in[24]; const float* bc  = (const float*)d_in[25];
    const float* Wf  = (const float*)d_in[26]; const float* bf  = (const float*)d_in[27];
    float* outp = (float*)d_out;

    // workspace carve
    char* ws = (char*)d_ws;
    size_t off = 0;
    auto carve = [&](size_t bytes) {
        char* p = ws + off;
        off = (off + bytes + 255) & ~(size_t)255;
        return p;
    };
    int* rp    = (int*)carve((NN + 1) * sizeof(int));
    int* cur   = (int*)carve((size_t)NN * sizeof(int));   // doubles as degree histogram
    int* part  = (int*)carve(512 * sizeof(int));
    int* offs  = (int*)carve(512 * sizeof(int));
    int* ssrc  = (int*)carve((size_t)EE * sizeof(int));
    int* seid  = (int*)carve((size_t)EE * sizeof(int));
    float* bigA = (float*)carve((size_t)NN * 256 * sizeof(float)); // Q|K|V|BASE -> g1 -> g3
    float* bigB = (float*)carve((size_t)NN * 256 * sizeof(float)); // h0|hs0|hs1|hs2 -> g2
    float* pl   = (float*)carve((size_t)NMG * 64 * sizeof(float));
    // optional CSR-ordered edge_attr copy (+102.4 MB) — use only if ws allows
    const size_t EAC_BYTES = (size_t)EE * 16 * sizeof(float);
    bool use_eac = (off + EAC_BYTES) <= ws_size;           // runtime-constant -> graph-safe
    float* eac = use_eac ? (float*)carve(EAC_BYTES) : nullptr;

    float* Q    = bigA;
    float* Km   = bigA + (size_t)NN * 64;
    float* V    = bigA + (size_t)NN * 128;
    float* BASE = bigA + (size_t)NN * 192;
    float* h0   = bigB;
    float* hA   = bigB + (size_t)NN * 64;
    float* hB   = bigB + (size_t)NN * 128;
    float* hC   = bigB + (size_t)NN * 192;
    float* g1 = bigA;
    float* g2 = bigB;
    float* g3 = bigA;

    const int* esrc = ei;
    const int* edst = ei + EE;

    // ---- CSR build (once; reused by all 4 layers)
    hipMemsetAsync(cur, 0, (size_t)NN * sizeof(int), stream);
    tf_hist<<<EE / 256, 256, 0, stream>>>(edst, cur);
    tf_scan1<<<391, 256, 0, stream>>>(cur, rp, part);
    tf_scan2<<<1, 512, 0, stream>>>(part, offs, 391);
    tf_scan3<<<392, 256, 0, stream>>>(rp, offs);
    hipMemsetAsync(cur, 0, (size_t)NN * sizeof(int), stream);
    tf_scatter<<<EE / 256, 256, 0, stream>>>(esrc, edst, rp, cur, ssrc, seid);
    if (use_eac)
        tf_ecopy<<<(EE * 4) / 256, 256, 0, stream>>>(seid, ea, eac);

    const int GB = (NN + 63) / 64;   // 1563 GEMM blocks
    const int AB = NN / 4;           // 25000 agg blocks

    // ---- conv1 (IN=128 -> 64)
    tf_gemm<0><<<GB, 256, 0, stream>>>(x, nullptr, nullptr, nullptr, nullptr, nullptr,
                                       Wq1, Wk1, Wv1, Ws1, bq1, bk1, bv1, bs1,
                                       Q, Km, V, BASE, 128, 0);
    if (use_eac)
        tf_agg<true><<<AB, 256, 0, stream>>>(Q, Km, V, BASE, rp, ssrc, seid, eac, We1, h0);
    else
        tf_agg<false><<<AB, 256, 0, stream>>>(Q, Km, V, BASE, rp, ssrc, seid, ea, We1, h0);

    // ---- stacked convs (64 -> 64), outputs kept for classifier concat
    const float* hin = h0;
    float* houts[3] = {hA, hB, hC};
    for (int l = 0; l < 3; ++l) {
        tf_gemm<0><<<GB, 256, 0, stream>>>(hin, nullptr, nullptr, nullptr, nullptr, nullptr,
                                           WqL + l * 4096, WkL + l * 4096, WvL + l * 4096, WsL + l * 4096,
                                           bqL + l * 64, bkL + l * 64, bvL + l * 64, bsL + l * 64,
                                           Q, Km, V, BASE, 64, 0);
        if (use_eac)
            tf_agg<true><<<AB, 256, 0, stream>>>(Q, Km, V, BASE, rp, ssrc, seid, eac,
                                                 WeL + l * 1024, houts[l]);
        else
            tf_agg<false><<<AB, 256, 0, stream>>>(Q, Km, V, BASE, rp, ssrc, seid, ea,
                                                  WeL + l * 1024, houts[l]);
        hin = houts[l];
    }

    // ---- global_add_pool on final h (hC)
    hipMemsetAsync(pl, 0, (size_t)NMG * 64 * sizeof(float), stream);
    tf_pool<<<AB, 256, 0, stream>>>(hC, bat, pl);

    // ---- classifier
    tf_gemm<1><<<GB, 256, 0, stream>>>(nullptr, hA, hB, hC, pl, bat,
                                       W1, nullptr, nullptr, nullptr,
                                       b1, nullptr, nullptr, nullptr,
                                       g1, nullptr, nullptr, nullptr, 256, 0);
    tf_gemm<2><<<GB, 256, 0, stream>>>(g1, nullptr, nullptr, nullptr, nullptr, nullptr,
                                       Wc, nullptr, nullptr, nullptr,
                                       bc, nullptr, nullptr, nullptr,
                                       g2, nullptr, nullptr, nullptr, 256, 1);
    tf_gemm<2><<<GB, 256, 0, stream>>>(g2, nullptr, nullptr, nullptr, nullptr, nullptr,
                                       Wc + 65536, nullptr, nullptr, nullptr,
                                       bc + 256, nullptr, nullptr, nullptr,
                                       g3, nullptr, nullptr, nullptr, 256, 1);
    tf_final<<<AB, 256, 0, stream>>>(g3, Wf, bf, outp);
}